// Round 10
// baseline (134.766 us; speedup 1.0000x reference)
//
#include <hip/hip_runtime.h>
#include <hip/hip_bf16.h>

#define CIN    32
#define NPIX   4096   // 64*64 spatial positions
#define DIM    64     // attention channels
#define LOG2E  1.4426950408889634f

#if __has_builtin(__builtin_amdgcn_exp2f)
#define EXP2(x) __builtin_amdgcn_exp2f(x)
#else
#define EXP2(x) exp2f(x)
#endif

typedef float  f32x4  __attribute__((ext_vector_type(4)));
typedef float  f32x16 __attribute__((ext_vector_type(16)));
typedef short  s16x8  __attribute__((ext_vector_type(8)));   // 8 bf16 = one 32x32x16 A/B fragment

#define ZERO16 {0.f,0.f,0.f,0.f,0.f,0.f,0.f,0.f,0.f,0.f,0.f,0.f,0.f,0.f,0.f,0.f}

__device__ __forceinline__ f32x16 mfma32(s16x8 a, s16x8 b, f32x16 c) {
    return __builtin_amdgcn_mfma_f32_32x32x16_bf16(a, b, c, 0, 0, 0);
}

// ---------------------------------------------------------------------------
// Layouts (all per batch b):
//  Q: row-major (N, 64), PRE-SCALED by log2(e).
//  K: 32x32x16 A-frag order: [s(128)][kt(4)][h2(2)][key(32)][j(8)]
//     element = K[pixel s*32+key][dim kt*16 + h2*8 + j]   (4 KB per tile s)
//  V: CONTIGUOUS-frag order of V^T: [s(128)][cht(2)][m(2)][hk(2)][ch'(32)][j(8)]
//     element = V[key s*32 + 16m + (j&3) + 8*(j>>2) + 4*hk][ch cht*32+ch']
//     (frag (cht,m) is one contiguous 1 KB block; addr = lane*16 + j*2)
//  No softmax shift anywhere: scores' = s*log2e <= ~30, exp2 safe in f32/bf16.
// ---------------------------------------------------------------------------

// ---------------------------------------------------------------------------
// Kernel A: QKV projection. Q row-major (scaled); K/V in 32x32 frag orders.
// ---------------------------------------------------------------------------
__global__ __launch_bounds__(256) void qkv_proj(
    const float* __restrict__ x,
    const float* __restrict__ wq, const float* __restrict__ bq,
    const float* __restrict__ wk, const float* __restrict__ bk,
    const float* __restrict__ wv, const float* __restrict__ bv,
    __hip_bfloat16* __restrict__ qb, __hip_bfloat16* __restrict__ kb,
    __hip_bfloat16* __restrict__ vb)
{
    __shared__ float Xs[CIN][64];        // [c_in][pixel]
    __shared__ float wT[3][CIN][DIM];    // [mat][c_in][c_out]; wT[0] pre-scaled

    const int tid = threadIdx.x;
    const int b   = blockIdx.y;
    const int bx  = blockIdx.x;
    const int n0  = bx * 64;

    for (int i = tid; i < 3 * CIN * DIM; i += 256) {
        int m = i >> 11, r = i & 2047, c = r >> 6, o = r & 63;
        const float* wsrc = (m == 0) ? wq : (m == 1) ? wk : wv;
        float wv0 = wsrc[o * CIN + c];
        wT[m][c][o] = (m == 0) ? wv0 * LOG2E : wv0;
    }
    for (int i = tid * 4; i < CIN * 64; i += 1024) {
        int c = i >> 6, p = i & 63;
        *(f32x4*)&Xs[c][p] = *(const f32x4*)&x[((size_t)b * CIN + c) * NPIX + n0 + p];
    }
    __syncthreads();

    const int w    = tid >> 6;
    const int lane = tid & 63;
    const int l16  = lane >> 2;
    const int quad = lane & 3;

    const int T  = bx * 4 + w;
    const int px = T * 16 + l16;

    float aq[2][8], ak[2][8];
    #pragma unroll
    for (int kb2 = 0; kb2 < 2; kb2++) {
        f32x4 bq0 = *(const f32x4*)&bq[kb2 * 32 + quad * 8];
        f32x4 bq1 = *(const f32x4*)&bq[kb2 * 32 + quad * 8 + 4];
        f32x4 bk0 = *(const f32x4*)&bk[kb2 * 32 + quad * 8];
        f32x4 bk1 = *(const f32x4*)&bk[kb2 * 32 + quad * 8 + 4];
        #pragma unroll
        for (int j = 0; j < 4; j++) {
            aq[kb2][j] = bq0[j] * LOG2E; aq[kb2][j + 4] = bq1[j] * LOG2E;
            ak[kb2][j] = bk0[j];         ak[kb2][j + 4] = bk1[j];
        }
    }
    #pragma unroll 8
    for (int c = 0; c < CIN; c++) {
        const float xc = Xs[c][w * 16 + l16];
        #pragma unroll
        for (int kb2 = 0; kb2 < 2; kb2++) {
            f32x4 q0 = *(const f32x4*)&wT[0][c][kb2 * 32 + quad * 8];
            f32x4 q1 = *(const f32x4*)&wT[0][c][kb2 * 32 + quad * 8 + 4];
            f32x4 k0 = *(const f32x4*)&wT[1][c][kb2 * 32 + quad * 8];
            f32x4 k1 = *(const f32x4*)&wT[1][c][kb2 * 32 + quad * 8 + 4];
            #pragma unroll
            for (int j = 0; j < 4; j++) {
                aq[kb2][j]     += xc * q0[j];
                aq[kb2][j + 4] += xc * q1[j];
                ak[kb2][j]     += xc * k0[j];
                ak[kb2][j + 4] += xc * k1[j];
            }
        }
    }
    // Q store row-major; K store in 32x32 A-frag order.
    {
        const int s   = px >> 5;
        const int key = px & 31;
        #pragma unroll
        for (int kb2 = 0; kb2 < 2; kb2++) {
            union { s16x8 v; __hip_bfloat16 h[8]; } pq, pk;
            #pragma unroll
            for (int j = 0; j < 8; j++) {
                pq.h[j] = __float2bfloat16(aq[kb2][j]);
                pk.h[j] = __float2bfloat16(ak[kb2][j]);
            }
            *(s16x8*)(qb + ((size_t)b * NPIX + px) * DIM + kb2 * 32 + quad * 8) = pq.v;
            const int kt = kb2 * 2 + (quad >> 1);
            const int h  = quad & 1;
            const size_t koff = (size_t)b * 262144
                + ((size_t)(s * 4 + kt) * 64 + h * 32 + key) * 8;
            *(s16x8*)(kb + koff) = pk.v;
        }
    }

    const int ch = w * 16 + l16;
    float av[2][8];
    {
        const float bvc = bv[ch];
        #pragma unroll
        for (int kh = 0; kh < 2; kh++)
            #pragma unroll
            for (int j = 0; j < 8; j++) av[kh][j] = bvc;
    }
    #pragma unroll 8
    for (int c = 0; c < CIN; c++) {
        const float wvc = wT[2][c][ch];
        f32x4 x0 = *(const f32x4*)&Xs[c][quad * 8];
        f32x4 x1 = *(const f32x4*)&Xs[c][quad * 8 + 4];
        f32x4 x2 = *(const f32x4*)&Xs[c][32 + quad * 8];
        f32x4 x3 = *(const f32x4*)&Xs[c][32 + quad * 8 + 4];
        #pragma unroll
        for (int j = 0; j < 4; j++) {
            av[0][j]     += x0[j] * wvc;
            av[0][j + 4] += x1[j] * wvc;
            av[1][j]     += x2[j] * wvc;
            av[1][j + 4] += x3[j] * wvc;
        }
    }
    // av[kh][jj] = V[key quad*8+jj (tile s=bx*2+kh)][ch].  Emit contiguous
    // frag order: kappa = quad*8+jj -> m = quad>>1, hk = jj>>2,
    // j' = (jj&3) + 4*(quad&1).
    #pragma unroll
    for (int kh = 0; kh < 2; kh++) {
        const int s = bx * 2 + kh;
        #pragma unroll
        for (int h = 0; h < 2; h++) {
            union { unsigned long long u; __hip_bfloat16 hh[4]; } pv;
            #pragma unroll
            for (int j = 0; j < 4; j++) pv.hh[j] = __float2bfloat16(av[kh][h * 4 + j]);
            const size_t voff = (size_t)b * 262144
                + (size_t)(s * 4 + (ch >> 5) * 2 + (quad >> 1)) * 512
                + (size_t)(h * 32 + (ch & 31)) * 8
                + 4 * (quad & 1);
            *(unsigned long long*)(vb + voff) = pv.u;
        }
    }
}

// ---------------------------------------------------------------------------
// Kernel B v9: TRUE 2 blocks/CU. Grid (8,64) = 512 blocks x 512 thr.
//   Per block: 64 q-rows; 8 waves = 2 q-groups(32 rows) x 4 key-quarters
//   (1024 keys = 32 tiles each). Per phase (32): wave w stages slot w
//   (slots 0-3 = K quarters, 4-7 = V quarters; 4 KB each, dbuf 64 KB);
//   each wave computes 1 tile: 4 S-MFMA (two 2-chains) + 4 PV-MFMA,
//   VALU row-sum. Two INDEPENDENT blocks per CU hide each other's
//   barrier/dependency stalls (R9's experiment finally run correctly:
//   R9 had 2-blocks/CU *capacity* but a 256-block grid = 1/CU resident).
//   Epilogue: 4-partial reduce (3 slots aliased into staging, 50.7 KB),
//   out-proj by quarter-0 waves. LDS 66.3 KB -> 2 blocks = 132.6 <= 160.
//   Spill guard: FETCH_SIZE ~8.3 MB / WRITE_SIZE 4 MB must hold.
// ---------------------------------------------------------------------------
__global__ __launch_bounds__(512, 4) void attn_fused(
    const __hip_bfloat16* __restrict__ qb,
    const __hip_bfloat16* __restrict__ kbf,
    const __hip_bfloat16* __restrict__ vbf,
    const float* __restrict__ wo, const float* __restrict__ bo,
    const float* __restrict__ x, float* __restrict__ y)
{
    __shared__ __align__(16) char sm[2][8][4096];   // 64 KB staging; epilogue aliases
    __shared__ float LRED2[3][2][32];               // row-sum partials 768 B

    float (*REDq)[2][64][33] = (float (*)[2][64][33])&sm[0][0][0]; // 50688 B alias

    const int tid  = threadIdx.x;
    const int w    = tid >> 6;          // wave 0..7
    const int g    = w >> 2;            // q-group (32 rows)
    const int kq   = w & 3;             // key quarter (1024 keys = 32 tiles)
    const int lane = tid & 63;
    const int q    = lane & 31;         // C/D column = q-row index
    const int hl   = lane >> 5;         // lane half
    const int b    = blockIdx.x;        // batch -> XCD affinity (lin%8 = b)
    const int row0 = blockIdx.y * 64 + g * 32;

    // Q B-frags (32x32x16): elem j at half hl -> dim kt*16 + hl*8 + j
    s16x8 qf[4];
    #pragma unroll
    for (int kt = 0; kt < 4; kt++)
        qf[kt] = *(const s16x8*)(qb + ((size_t)b * NPIX + row0 + q) * DIM
                                 + kt * 16 + hl * 8);

    f32x16 o0 = ZERO16, o1 = ZERO16;    // O^T[ch 0-31][q], O^T[ch 32-63][q]
    float lsacc = 0.f;                  // per-lane partial row-sum

    // staging: wave w stages slot w = kv(1)|quarter(2): kv = w>>2, qs = w&3.
    const char* stbase = ((w >> 2) ? (const char*)vbf : (const char*)kbf)
                       + (size_t)b * 524288
                       + (size_t)(w & 3) * 131072     // 32 tiles per quarter
                       + (size_t)lane * 16;
    char* std0 = &sm[0][w][lane * 16];
    char* std1 = &sm[1][w][lane * 16];

    // prologue: stage tile 0 into buf 0
    #pragma unroll
    for (int i = 0; i < 4; i++)
        *(f32x4*)(std0 + i * 1024) = *(const f32x4*)(stbase + i * 1024);
    __syncthreads();

    int cur = 0;
    for (int p = 0; p < 32; ++p) {
        // K fragments from current buffer (contiguous 1 KB frags: conflict-free)
        const char* Kl = sm[cur][kq];
        s16x8 kf[4];
        #pragma unroll
        for (int i = 0; i < 4; i++)
            kf[i] = *(const s16x8*)(Kl + i * 1024 + lane * 16);

        // issue next-phase staging loads early (full phase to land)
        const size_t srcoff = (size_t)((p < 31) ? p + 1 : 31) * 4096;
        f32x4 r0 = *(const f32x4*)(stbase + srcoff);
        f32x4 r1 = *(const f32x4*)(stbase + srcoff + 1024);
        f32x4 r2 = *(const f32x4*)(stbase + srcoff + 2048);
        f32x4 r3 = *(const f32x4*)(stbase + srcoff + 3072);

        // S^T: two independent 2-chains over the dim halves
        __builtin_amdgcn_s_setprio(1);
        f32x16 sA = ZERO16, sB = ZERO16;
        sA = mfma32(kf[0], qf[0], sA);
        sB = mfma32(kf[2], qf[2], sB);
        sA = mfma32(kf[1], qf[1], sA);
        sB = mfma32(kf[3], qf[3], sB);
        __builtin_amdgcn_s_setprio(0);

        // P^T = exp2(S^T) -> bf16 B-frags; VALU row-sum
        union { s16x8 v; __hip_bfloat16 h8[8]; } p0, p1;
        #pragma unroll
        for (int j = 0; j < 8; j++) {
            float e0 = EXP2(sA[j] + sB[j]);
            float e1 = EXP2(sA[8 + j] + sB[8 + j]);
            lsacc += e0 + e1;
            p0.h8[j] = __float2bfloat16(e0);
            p1.h8[j] = __float2bfloat16(e1);
        }

        // V fragments
        const char* Vl = sm[cur][4 + kq];
        s16x8 vv[4];
        #pragma unroll
        for (int i = 0; i < 4; i++)
            vv[i] = *(const s16x8*)(Vl + i * 1024 + lane * 16);

        // O^T += V^T P^T  (two independent 2-chains)
        __builtin_amdgcn_s_setprio(1);
        o0 = mfma32(vv[0], p0.v, o0);
        o1 = mfma32(vv[2], p0.v, o1);
        o0 = mfma32(vv[1], p1.v, o0);
        o1 = mfma32(vv[3], p1.v, o1);
        __builtin_amdgcn_s_setprio(0);

        // write staged tile into the other buffer, then phase barrier
        char* dst = cur ? std0 : std1;
        *(f32x4*)(dst)        = r0;
        *(f32x4*)(dst + 1024) = r1;
        *(f32x4*)(dst + 2048) = r2;
        *(f32x4*)(dst + 3072) = r3;
        __syncthreads();
        cur ^= 1;
    }

    // cross-half row-sum combine (both lane-halves hold same q, disjoint keys)
    lsacc += __shfl_xor(lsacc, 32, 64);

    // ---- combine the four key-quarters per q-group (REDq aliases staging) ----
    if (kq != 0) {
        #pragma unroll
        for (int i = 0; i < 16; i++) {
            const int rr = (i & 3) + 8 * (i >> 2) + 4 * hl;
            REDq[kq - 1][g][rr][q]      = o0[i];
            REDq[kq - 1][g][32 + rr][q] = o1[i];
        }
        if (hl == 0) LRED2[kq - 1][g][q] = lsacc;
    }
    __syncthreads();

    if (kq == 0) {
        #pragma unroll
        for (int sl = 0; sl < 3; sl++) {
            lsacc += LRED2[sl][g][q];
            #pragma unroll
            for (int i = 0; i < 16; i++) {
                const int rr = (i & 3) + 8 * (i >> 2) + 4 * hl;
                o0[i] += REDq[sl][g][rr][q];
                o1[i] += REDq[sl][g][32 + rr][q];
            }
        }
        const float inv = 1.0f / lsacc;

        // normalized O^T -> B-frags per 16-ch group (direct from registers)
        s16x8 pbo[4];
        #pragma unroll
        for (int gg = 0; gg < 4; gg++) {
            union { s16x8 v; __hip_bfloat16 h8[8]; } pk;
            #pragma unroll
            for (int j = 0; j < 8; j++) {
                const float vv2 = (gg < 2) ? o0[(gg & 1) * 8 + j] : o1[(gg & 1) * 8 + j];
                pk.h8[j] = __float2bfloat16(vv2 * inv);
            }
            pbo[gg] = pk.v;
        }

        // wo A-frags with the key/ch relabeling mu(gg,hl,j)
        s16x8 aw[4];
        #pragma unroll
        for (int gg = 0; gg < 4; gg++) {
            f32x4 w0 = *(const f32x4*)(wo + (size_t)q * DIM + gg * 16 + hl * 4);
            f32x4 w1 = *(const f32x4*)(wo + (size_t)q * DIM + gg * 16 + 8 + hl * 4);
            union { s16x8 v; __hip_bfloat16 h8[8]; } wf;
            #pragma unroll
            for (int j = 0; j < 4; j++) {
                wf.h8[j]     = __float2bfloat16(w0[j]);
                wf.h8[4 + j] = __float2bfloat16(w1[j]);
            }
            aw[gg] = wf.v;
        }

        // Y^T[out][q] = wo x ONorm^T  (single 32x32 tile, K=64 over 4 mfmas)
        f32x16 d = ZERO16;
        #pragma unroll
        for (int gg = 0; gg < 4; gg++)
            d = mfma32(aw[gg], pbo[gg], d);

        // bias + residual + store y (B, 32, 4096) fp32
        #pragma unroll
        for (int i = 0; i < 16; i++) {
            const int out = (i & 3) + 8 * (i >> 2) + 4 * hl;
            const int row = row0 + q;
            const size_t xi = ((size_t)b * CIN + out) * NPIX + row;
            y[xi] = d[i] + bo[out] + x[xi];
        }
    }
}

// ---------------------------------------------------------------------------
extern "C" void kernel_launch(void* const* d_in, const int* in_sizes, int n_in,
                              void* d_out, int out_size, void* d_ws, size_t ws_size,
                              hipStream_t stream)
{
    const float* x  = (const float*)d_in[0];
    const float* wq = (const float*)d_in[1];
    const float* bq = (const float*)d_in[2];
    const float* wk = (const float*)d_in[3];
    const float* bk = (const float*)d_in[4];
    const float* wv = (const float*)d_in[5];
    const float* bv = (const float*)d_in[6];
    const float* wo = (const float*)d_in[7];
    const float* bo = (const float*)d_in[8];
    float* y = (float*)d_out;

    // workspace: qb 4MB (row-major, log2e-scaled) | kb 4MB | vb 4MB (frag orders)
    char* ws = (char*)d_ws;
    __hip_bfloat16* qb = (__hip_bfloat16*)(ws);
    __hip_bfloat16* kb = (__hip_bfloat16*)(ws + (4u << 20));
    __hip_bfloat16* vb = (__hip_bfloat16*)(ws + (8u << 20));

    qkv_proj<<<dim3(64, 8), dim3(256), 0, stream>>>(x, wq, bq, wk, bk, wv, bv, qb, kb, vb);
    attn_fused<<<dim3(8, 64), dim3(512), 0, stream>>>(qb, kb, vb, wo, bo, x, y);
}

// Round 11
// 131.868 us; speedup vs baseline: 1.0220x; 1.0220x over previous
//
#include <hip/hip_runtime.h>
#include <hip/hip_bf16.h>

#define CIN    32
#define NPIX   4096   // 64*64 spatial positions
#define DIM    64     // attention channels
#define LOG2E  1.4426950408889634f

#if __has_builtin(__builtin_amdgcn_exp2f)
#define EXP2(x) __builtin_amdgcn_exp2f(x)
#else
#define EXP2(x) exp2f(x)
#endif

typedef float  f32x4  __attribute__((ext_vector_type(4)));
typedef float  f32x16 __attribute__((ext_vector_type(16)));
typedef short  s16x8  __attribute__((ext_vector_type(8)));   // 8 bf16 = one 32x32x16 A/B fragment

#define ZERO16 {0.f,0.f,0.f,0.f,0.f,0.f,0.f,0.f,0.f,0.f,0.f,0.f,0.f,0.f,0.f,0.f}

__device__ __forceinline__ f32x16 mfma32(s16x8 a, s16x8 b, f32x16 c) {
    return __builtin_amdgcn_mfma_f32_32x32x16_bf16(a, b, c, 0, 0, 0);
}

// ---------------------------------------------------------------------------
// Layouts (all per batch b):
//  Q: row-major (N, 64), PRE-SCALED by log2(e).
//  K: 32x32x16 A-frag order: [s(128)][kt(4)][h2(2)][key(32)][j(8)]
//     element = K[pixel s*32+key][dim kt*16 + h2*8 + j]   (4 KB per tile s)
//  V: CONTIGUOUS-frag order of V^T: [s(128)][cht(2)][m(2)][hk(2)][ch'(32)][j(8)]
//     element = V[key s*32 + 16m + (j&3) + 8*(j>>2) + 4*hk][ch cht*32+ch']
//     (frag (cht,m) is one contiguous 1 KB block; addr = lane*16 + j*2)
//  No softmax shift anywhere: scores' = s*log2e <= ~30, exp2 safe in f32/bf16.
// ---------------------------------------------------------------------------

// ---------------------------------------------------------------------------
// Kernel A: QKV projection. Q row-major (scaled); K/V in 32x32 frag orders.
// ---------------------------------------------------------------------------
__global__ __launch_bounds__(256) void qkv_proj(
    const float* __restrict__ x,
    const float* __restrict__ wq, const float* __restrict__ bq,
    const float* __restrict__ wk, const float* __restrict__ bk,
    const float* __restrict__ wv, const float* __restrict__ bv,
    __hip_bfloat16* __restrict__ qb, __hip_bfloat16* __restrict__ kb,
    __hip_bfloat16* __restrict__ vb)
{
    __shared__ float Xs[CIN][64];        // [c_in][pixel]
    __shared__ float wT[3][CIN][DIM];    // [mat][c_in][c_out]; wT[0] pre-scaled

    const int tid = threadIdx.x;
    const int b   = blockIdx.y;
    const int bx  = blockIdx.x;
    const int n0  = bx * 64;

    for (int i = tid; i < 3 * CIN * DIM; i += 256) {
        int m = i >> 11, r = i & 2047, c = r >> 6, o = r & 63;
        const float* wsrc = (m == 0) ? wq : (m == 1) ? wk : wv;
        float wv0 = wsrc[o * CIN + c];
        wT[m][c][o] = (m == 0) ? wv0 * LOG2E : wv0;
    }
    for (int i = tid * 4; i < CIN * 64; i += 1024) {
        int c = i >> 6, p = i & 63;
        *(f32x4*)&Xs[c][p] = *(const f32x4*)&x[((size_t)b * CIN + c) * NPIX + n0 + p];
    }
    __syncthreads();

    const int w    = tid >> 6;
    const int lane = tid & 63;
    const int l16  = lane >> 2;
    const int quad = lane & 3;

    const int T  = bx * 4 + w;
    const int px = T * 16 + l16;

    float aq[2][8], ak[2][8];
    #pragma unroll
    for (int kb2 = 0; kb2 < 2; kb2++) {
        f32x4 bq0 = *(const f32x4*)&bq[kb2 * 32 + quad * 8];
        f32x4 bq1 = *(const f32x4*)&bq[kb2 * 32 + quad * 8 + 4];
        f32x4 bk0 = *(const f32x4*)&bk[kb2 * 32 + quad * 8];
        f32x4 bk1 = *(const f32x4*)&bk[kb2 * 32 + quad * 8 + 4];
        #pragma unroll
        for (int j = 0; j < 4; j++) {
            aq[kb2][j] = bq0[j] * LOG2E; aq[kb2][j + 4] = bq1[j] * LOG2E;
            ak[kb2][j] = bk0[j];         ak[kb2][j + 4] = bk1[j];
        }
    }
    #pragma unroll 8
    for (int c = 0; c < CIN; c++) {
        const float xc = Xs[c][w * 16 + l16];
        #pragma unroll
        for (int kb2 = 0; kb2 < 2; kb2++) {
            f32x4 q0 = *(const f32x4*)&wT[0][c][kb2 * 32 + quad * 8];
            f32x4 q1 = *(const f32x4*)&wT[0][c][kb2 * 32 + quad * 8 + 4];
            f32x4 k0 = *(const f32x4*)&wT[1][c][kb2 * 32 + quad * 8];
            f32x4 k1 = *(const f32x4*)&wT[1][c][kb2 * 32 + quad * 8 + 4];
            #pragma unroll
            for (int j = 0; j < 4; j++) {
                aq[kb2][j]     += xc * q0[j];
                aq[kb2][j + 4] += xc * q1[j];
                ak[kb2][j]     += xc * k0[j];
                ak[kb2][j + 4] += xc * k1[j];
            }
        }
    }
    // Q store row-major; K store in 32x32 A-frag order.
    {
        const int s   = px >> 5;
        const int key = px & 31;
        #pragma unroll
        for (int kb2 = 0; kb2 < 2; kb2++) {
            union { s16x8 v; __hip_bfloat16 h[8]; } pq, pk;
            #pragma unroll
            for (int j = 0; j < 8; j++) {
                pq.h[j] = __float2bfloat16(aq[kb2][j]);
                pk.h[j] = __float2bfloat16(ak[kb2][j]);
            }
            *(s16x8*)(qb + ((size_t)b * NPIX + px) * DIM + kb2 * 32 + quad * 8) = pq.v;
            const int kt = kb2 * 2 + (quad >> 1);
            const int h  = quad & 1;
            const size_t koff = (size_t)b * 262144
                + ((size_t)(s * 4 + kt) * 64 + h * 32 + key) * 8;
            *(s16x8*)(kb + koff) = pk.v;
        }
    }

    const int ch = w * 16 + l16;
    float av[2][8];
    {
        const float bvc = bv[ch];
        #pragma unroll
        for (int kh = 0; kh < 2; kh++)
            #pragma unroll
            for (int j = 0; j < 8; j++) av[kh][j] = bvc;
    }
    #pragma unroll 8
    for (int c = 0; c < CIN; c++) {
        const float wvc = wT[2][c][ch];
        f32x4 x0 = *(const f32x4*)&Xs[c][quad * 8];
        f32x4 x1 = *(const f32x4*)&Xs[c][quad * 8 + 4];
        f32x4 x2 = *(const f32x4*)&Xs[c][32 + quad * 8];
        f32x4 x3 = *(const f32x4*)&Xs[c][32 + quad * 8 + 4];
        #pragma unroll
        for (int j = 0; j < 4; j++) {
            av[0][j]     += x0[j] * wvc;
            av[0][j + 4] += x1[j] * wvc;
            av[1][j]     += x2[j] * wvc;
            av[1][j + 4] += x3[j] * wvc;
        }
    }
    // av[kh][jj] = V[key quad*8+jj (tile s=bx*2+kh)][ch].  Emit contiguous
    // frag order: kappa = quad*8+jj -> m = quad>>1, hk = jj>>2,
    // j' = (jj&3) + 4*(quad&1).
    #pragma unroll
    for (int kh = 0; kh < 2; kh++) {
        const int s = bx * 2 + kh;
        #pragma unroll
        for (int h = 0; h < 2; h++) {
            union { unsigned long long u; __hip_bfloat16 hh[4]; } pv;
            #pragma unroll
            for (int j = 0; j < 4; j++) pv.hh[j] = __float2bfloat16(av[kh][h * 4 + j]);
            const size_t voff = (size_t)b * 262144
                + (size_t)(s * 4 + (ch >> 5) * 2 + (quad >> 1)) * 512
                + (size_t)(h * 32 + (ch & 31)) * 8
                + 4 * (quad & 1);
            *(unsigned long long*)(vb + voff) = pv.u;
        }
    }
}

// ---------------------------------------------------------------------------
// Kernel B v10: v9 geometry (512 blocks x 512 thr, 2 q-groups x 4 quarters,
// true 2 blocks/CU) with the two heavy pipes shrunk:
//   1. V BYPASSES LDS: fragments are contiguous 1 KB blocks, read direct
//      from global (same bytes/lanes as the staged path). LDS traffic/CU/
//      phase 192 -> 96 KB; staging loads halve. L2 cost +256 MB (V read
//      once per q-group) -- 19 TB/s at target, under the 34.5 ceiling.
//   2. Single 4-deep S chain: kills 16 sA+sB VALU adds per tile.
//   3. LDS = 50.7 KB (32 KB K-dbuf; epilogue REDq aliased over staging).
//   K staging split: wave w stages half (w&1) of K slot (w>>1).
//   Spill guard: FETCH_SIZE ~8.3 MB / WRITE_SIZE 4 MB must hold.
// ---------------------------------------------------------------------------
__global__ __launch_bounds__(512, 4) void attn_fused(
    const __hip_bfloat16* __restrict__ qb,
    const __hip_bfloat16* __restrict__ kbf,
    const __hip_bfloat16* __restrict__ vbf,
    const float* __restrict__ wo, const float* __restrict__ bo,
    const float* __restrict__ x, float* __restrict__ y)
{
    __shared__ __align__(16) char smraw[50688];     // 32 KB K-dbuf; epilogue alias
    __shared__ float LRED2[3][2][32];               // row-sum partials 768 B

    char (*smK)[4][4096]     = (char (*)[4][4096])smraw;         // [buf][slot]
    float (*REDq)[2][64][33] = (float (*)[2][64][33])smraw;      // 50688 B alias

    const int tid  = threadIdx.x;
    const int w    = tid >> 6;          // wave 0..7
    const int g    = w >> 2;            // q-group (32 rows)
    const int kq   = w & 3;             // key quarter (1024 keys = 32 tiles)
    const int lane = tid & 63;
    const int q    = lane & 31;         // C/D column = q-row index
    const int hl   = lane >> 5;         // lane half
    const int b    = blockIdx.x;        // batch -> XCD affinity (lin%8 = b)
    const int row0 = blockIdx.y * 64 + g * 32;

    // Q B-frags (32x32x16): elem j at half hl -> dim kt*16 + hl*8 + j
    s16x8 qf[4];
    #pragma unroll
    for (int kt = 0; kt < 4; kt++)
        qf[kt] = *(const s16x8*)(qb + ((size_t)b * NPIX + row0 + q) * DIM
                                 + kt * 16 + hl * 8);

    f32x16 o0 = ZERO16, o1 = ZERO16;    // O^T[ch 0-31][q], O^T[ch 32-63][q]
    float lsacc = 0.f;                  // per-lane partial row-sum

    // K staging: wave w stages half (w&1) of slot (w>>1); 2 KB per wave/phase
    const char* kst = (const char*)kbf + (size_t)b * 524288
                    + (size_t)(w >> 1) * 131072
                    + (size_t)(w & 1) * 2048 + (size_t)lane * 16;
    char* std0 = &smK[0][w >> 1][(w & 1) * 2048 + lane * 16];
    char* std1 = &smK[1][w >> 1][(w & 1) * 2048 + lane * 16];

    // V direct-global base for this wave's quarter (contiguous 1 KB frags)
    const char* vbase = (const char*)vbf + (size_t)b * 524288
                      + (size_t)kq * 131072 + (size_t)lane * 16;

    // prologue: stage K tile 0 into buf 0
    *(f32x4*)(std0)        = *(const f32x4*)(kst);
    *(f32x4*)(std0 + 1024) = *(const f32x4*)(kst + 1024);
    __syncthreads();

    int cur = 0;
    for (int p = 0; p < 32; ++p) {
        // V tile p: direct global loads (consumed only after S+exp2 -- slack)
        s16x8 vv[4];
        #pragma unroll
        for (int i = 0; i < 4; i++)
            vv[i] = *(const s16x8*)(vbase + (size_t)p * 4096 + i * 1024);

        // K fragments from current LDS buffer (contiguous: conflict-free)
        const char* Kl = smK[cur][kq];
        s16x8 kf[4];
        #pragma unroll
        for (int i = 0; i < 4; i++)
            kf[i] = *(const s16x8*)(Kl + i * 1024 + lane * 16);

        // stage K tile p+1: issue loads early (full phase of slack)
        const size_t so = (size_t)((p < 31) ? p + 1 : 31) * 4096;
        f32x4 r0 = *(const f32x4*)(kst + so);
        f32x4 r1 = *(const f32x4*)(kst + so + 1024);

        // S^T: single 4-deep chain (no cross-chain add)
        __builtin_amdgcn_s_setprio(1);
        f32x16 s = ZERO16;
        s = mfma32(kf[0], qf[0], s);
        s = mfma32(kf[1], qf[1], s);
        s = mfma32(kf[2], qf[2], s);
        s = mfma32(kf[3], qf[3], s);
        __builtin_amdgcn_s_setprio(0);

        // P^T = exp2(S^T) -> bf16 B-frags; VALU row-sum
        union { s16x8 v; __hip_bfloat16 h8[8]; } p0, p1;
        #pragma unroll
        for (int j = 0; j < 8; j++) {
            float e0 = EXP2(s[j]);
            float e1 = EXP2(s[8 + j]);
            lsacc += e0 + e1;
            p0.h8[j] = __float2bfloat16(e0);
            p1.h8[j] = __float2bfloat16(e1);
        }

        // O^T += V^T P^T  (two independent 2-chains)
        __builtin_amdgcn_s_setprio(1);
        o0 = mfma32(vv[0], p0.v, o0);
        o1 = mfma32(vv[2], p0.v, o1);
        o0 = mfma32(vv[1], p1.v, o0);
        o1 = mfma32(vv[3], p1.v, o1);
        __builtin_amdgcn_s_setprio(0);

        // write staged K into the other buffer, then phase barrier
        char* dst = cur ? std0 : std1;
        *(f32x4*)(dst)        = r0;
        *(f32x4*)(dst + 1024) = r1;
        __syncthreads();
        cur ^= 1;
    }

    // cross-half row-sum combine (both lane-halves hold same q, disjoint keys)
    lsacc += __shfl_xor(lsacc, 32, 64);

    // ---- combine the four key-quarters per q-group (REDq aliases staging) ----
    if (kq != 0) {
        #pragma unroll
        for (int i = 0; i < 16; i++) {
            const int rr = (i & 3) + 8 * (i >> 2) + 4 * hl;
            REDq[kq - 1][g][rr][q]      = o0[i];
            REDq[kq - 1][g][32 + rr][q] = o1[i];
        }
        if (hl == 0) LRED2[kq - 1][g][q] = lsacc;
    }
    __syncthreads();

    if (kq == 0) {
        #pragma unroll
        for (int sl = 0; sl < 3; sl++) {
            lsacc += LRED2[sl][g][q];
            #pragma unroll
            for (int i = 0; i < 16; i++) {
                const int rr = (i & 3) + 8 * (i >> 2) + 4 * hl;
                o0[i] += REDq[sl][g][rr][q];
                o1[i] += REDq[sl][g][32 + rr][q];
            }
        }
        const float inv = 1.0f / lsacc;

        // normalized O^T -> B-frags per 16-ch group (direct from registers)
        s16x8 pbo[4];
        #pragma unroll
        for (int gg = 0; gg < 4; gg++) {
            union { s16x8 v; __hip_bfloat16 h8[8]; } pk;
            #pragma unroll
            for (int j = 0; j < 8; j++) {
                const float vv2 = (gg < 2) ? o0[(gg & 1) * 8 + j] : o1[(gg & 1) * 8 + j];
                pk.h8[j] = __float2bfloat16(vv2 * inv);
            }
            pbo[gg] = pk.v;
        }

        // wo A-frags with the key/ch relabeling mu(gg,hl,j)
        s16x8 aw[4];
        #pragma unroll
        for (int gg = 0; gg < 4; gg++) {
            f32x4 w0 = *(const f32x4*)(wo + (size_t)q * DIM + gg * 16 + hl * 4);
            f32x4 w1 = *(const f32x4*)(wo + (size_t)q * DIM + gg * 16 + 8 + hl * 4);
            union { s16x8 v; __hip_bfloat16 h8[8]; } wf;
            #pragma unroll
            for (int j = 0; j < 4; j++) {
                wf.h8[j]     = __float2bfloat16(w0[j]);
                wf.h8[4 + j] = __float2bfloat16(w1[j]);
            }
            aw[gg] = wf.v;
        }

        // Y^T[out][q] = wo x ONorm^T  (single 32x32 tile, K=64 over 4 mfmas)
        f32x16 d = ZERO16;
        #pragma unroll
        for (int gg = 0; gg < 4; gg++)
            d = mfma32(aw[gg], pbo[gg], d);

        // bias + residual + store y (B, 32, 4096) fp32
        #pragma unroll
        for (int i = 0; i < 16; i++) {
            const int out = (i & 3) + 8 * (i >> 2) + 4 * hl;
            const int row = row0 + q;
            const size_t xi = ((size_t)b * CIN + out) * NPIX + row;
            y[xi] = d[i] + bo[out] + x[xi];
        }
    }
}

// ---------------------------------------------------------------------------
extern "C" void kernel_launch(void* const* d_in, const int* in_sizes, int n_in,
                              void* d_out, int out_size, void* d_ws, size_t ws_size,
                              hipStream_t stream)
{
    const float* x  = (const float*)d_in[0];
    const float* wq = (const float*)d_in[1];
    const float* bq = (const float*)d_in[2];
    const float* wk = (const float*)d_in[3];
    const float* bk = (const float*)d_in[4];
    const float* wv = (const float*)d_in[5];
    const float* bv = (const float*)d_in[6];
    const float* wo = (const float*)d_in[7];
    const float* bo = (const float*)d_in[8];
    float* y = (float*)d_out;

    // workspace: qb 4MB (row-major, log2e-scaled) | kb 4MB | vb 4MB (frag orders)
    char* ws = (char*)d_ws;
    __hip_bfloat16* qb = (__hip_bfloat16*)(ws);
    __hip_bfloat16* kb = (__hip_bfloat16*)(ws + (4u << 20));
    __hip_bfloat16* vb = (__hip_bfloat16*)(ws + (8u << 20));

    qkv_proj<<<dim3(64, 8), dim3(256), 0, stream>>>(x, wq, bq, wk, bk, wv, bv, qb, kb, vb);
    attn_fused<<<dim3(8, 64), dim3(512), 0, stream>>>(qb, kb, vb, wo, bo, x, y);
}

// Round 12
// 126.950 us; speedup vs baseline: 1.0616x; 1.0387x over previous
//
#include <hip/hip_runtime.h>
#include <hip/hip_bf16.h>

#define CIN    32
#define NPIX   4096   // 64*64 spatial positions
#define DIM    64     // attention channels
#define LOG2E  1.4426950408889634f

#if __has_builtin(__builtin_amdgcn_exp2f)
#define EXP2(x) __builtin_amdgcn_exp2f(x)
#else
#define EXP2(x) exp2f(x)
#endif

typedef float  f32x4  __attribute__((ext_vector_type(4)));
typedef float  f32x16 __attribute__((ext_vector_type(16)));
typedef short  s16x8  __attribute__((ext_vector_type(8)));   // 8 bf16 = one 32x32x16 A/B fragment

#define ZERO16 {0.f,0.f,0.f,0.f,0.f,0.f,0.f,0.f,0.f,0.f,0.f,0.f,0.f,0.f,0.f,0.f}

__device__ __forceinline__ f32x16 mfma32(s16x8 a, s16x8 b, f32x16 c) {
    return __builtin_amdgcn_mfma_f32_32x32x16_bf16(a, b, c, 0, 0, 0);
}

// ---------------------------------------------------------------------------
// Layouts (all per batch b):
//  Q: row-major (N, 64), PRE-SCALED by log2(e).
//  K: 32x32x16 A-frag order: [s(128)][kt(4)][h2(2)][key(32)][j(8)]
//     element = K[pixel s*32+key][dim kt*16 + h2*8 + j]   (4 KB per tile s)
//  V: CONTIGUOUS-frag order of V^T: [s(128)][cht(2)][m(2)][hk(2)][ch'(32)][j(8)]
//     element = V[key s*32 + 16m + (j&3) + 8*(j>>2) + 4*hk][ch cht*32+ch']
//     (frag (cht,m) is one contiguous 1 KB block; addr = lane*16 + j*2)
//  No softmax shift anywhere: scores' = s*log2e <= ~30, exp2 safe in f32/bf16.
// ---------------------------------------------------------------------------

// ---------------------------------------------------------------------------
// Kernel A: QKV projection. Q row-major (scaled); K/V in 32x32 frag orders.
// ---------------------------------------------------------------------------
__global__ __launch_bounds__(256) void qkv_proj(
    const float* __restrict__ x,
    const float* __restrict__ wq, const float* __restrict__ bq,
    const float* __restrict__ wk, const float* __restrict__ bk,
    const float* __restrict__ wv, const float* __restrict__ bv,
    __hip_bfloat16* __restrict__ qb, __hip_bfloat16* __restrict__ kb,
    __hip_bfloat16* __restrict__ vb)
{
    __shared__ float Xs[CIN][64];        // [c_in][pixel]
    __shared__ float wT[3][CIN][DIM];    // [mat][c_in][c_out]; wT[0] pre-scaled

    const int tid = threadIdx.x;
    const int b   = blockIdx.y;
    const int bx  = blockIdx.x;
    const int n0  = bx * 64;

    for (int i = tid; i < 3 * CIN * DIM; i += 256) {
        int m = i >> 11, r = i & 2047, c = r >> 6, o = r & 63;
        const float* wsrc = (m == 0) ? wq : (m == 1) ? wk : wv;
        float wv0 = wsrc[o * CIN + c];
        wT[m][c][o] = (m == 0) ? wv0 * LOG2E : wv0;
    }
    for (int i = tid * 4; i < CIN * 64; i += 1024) {
        int c = i >> 6, p = i & 63;
        *(f32x4*)&Xs[c][p] = *(const f32x4*)&x[((size_t)b * CIN + c) * NPIX + n0 + p];
    }
    __syncthreads();

    const int w    = tid >> 6;
    const int lane = tid & 63;
    const int l16  = lane >> 2;
    const int quad = lane & 3;

    const int T  = bx * 4 + w;
    const int px = T * 16 + l16;

    float aq[2][8], ak[2][8];
    #pragma unroll
    for (int kb2 = 0; kb2 < 2; kb2++) {
        f32x4 bq0 = *(const f32x4*)&bq[kb2 * 32 + quad * 8];
        f32x4 bq1 = *(const f32x4*)&bq[kb2 * 32 + quad * 8 + 4];
        f32x4 bk0 = *(const f32x4*)&bk[kb2 * 32 + quad * 8];
        f32x4 bk1 = *(const f32x4*)&bk[kb2 * 32 + quad * 8 + 4];
        #pragma unroll
        for (int j = 0; j < 4; j++) {
            aq[kb2][j] = bq0[j] * LOG2E; aq[kb2][j + 4] = bq1[j] * LOG2E;
            ak[kb2][j] = bk0[j];         ak[kb2][j + 4] = bk1[j];
        }
    }
    #pragma unroll 8
    for (int c = 0; c < CIN; c++) {
        const float xc = Xs[c][w * 16 + l16];
        #pragma unroll
        for (int kb2 = 0; kb2 < 2; kb2++) {
            f32x4 q0 = *(const f32x4*)&wT[0][c][kb2 * 32 + quad * 8];
            f32x4 q1 = *(const f32x4*)&wT[0][c][kb2 * 32 + quad * 8 + 4];
            f32x4 k0 = *(const f32x4*)&wT[1][c][kb2 * 32 + quad * 8];
            f32x4 k1 = *(const f32x4*)&wT[1][c][kb2 * 32 + quad * 8 + 4];
            #pragma unroll
            for (int j = 0; j < 4; j++) {
                aq[kb2][j]     += xc * q0[j];
                aq[kb2][j + 4] += xc * q1[j];
                ak[kb2][j]     += xc * k0[j];
                ak[kb2][j + 4] += xc * k1[j];
            }
        }
    }
    // Q store row-major; K store in 32x32 A-frag order.
    {
        const int s   = px >> 5;
        const int key = px & 31;
        #pragma unroll
        for (int kb2 = 0; kb2 < 2; kb2++) {
            union { s16x8 v; __hip_bfloat16 h[8]; } pq, pk;
            #pragma unroll
            for (int j = 0; j < 8; j++) {
                pq.h[j] = __float2bfloat16(aq[kb2][j]);
                pk.h[j] = __float2bfloat16(ak[kb2][j]);
            }
            *(s16x8*)(qb + ((size_t)b * NPIX + px) * DIM + kb2 * 32 + quad * 8) = pq.v;
            const int kt = kb2 * 2 + (quad >> 1);
            const int h  = quad & 1;
            const size_t koff = (size_t)b * 262144
                + ((size_t)(s * 4 + kt) * 64 + h * 32 + key) * 8;
            *(s16x8*)(kb + koff) = pk.v;
        }
    }

    const int ch = w * 16 + l16;
    float av[2][8];
    {
        const float bvc = bv[ch];
        #pragma unroll
        for (int kh = 0; kh < 2; kh++)
            #pragma unroll
            for (int j = 0; j < 8; j++) av[kh][j] = bvc;
    }
    #pragma unroll 8
    for (int c = 0; c < CIN; c++) {
        const float wvc = wT[2][c][ch];
        f32x4 x0 = *(const f32x4*)&Xs[c][quad * 8];
        f32x4 x1 = *(const f32x4*)&Xs[c][quad * 8 + 4];
        f32x4 x2 = *(const f32x4*)&Xs[c][32 + quad * 8];
        f32x4 x3 = *(const f32x4*)&Xs[c][32 + quad * 8 + 4];
        #pragma unroll
        for (int j = 0; j < 4; j++) {
            av[0][j]     += x0[j] * wvc;
            av[0][j + 4] += x1[j] * wvc;
            av[1][j]     += x2[j] * wvc;
            av[1][j + 4] += x3[j] * wvc;
        }
    }
    // av[kh][jj] = V[key quad*8+jj (tile s=bx*2+kh)][ch].  Emit contiguous
    // frag order: kappa = quad*8+jj -> m = quad>>1, hk = jj>>2,
    // j' = (jj&3) + 4*(quad&1).
    #pragma unroll
    for (int kh = 0; kh < 2; kh++) {
        const int s = bx * 2 + kh;
        #pragma unroll
        for (int h = 0; h < 2; h++) {
            union { unsigned long long u; __hip_bfloat16 hh[4]; } pv;
            #pragma unroll
            for (int j = 0; j < 4; j++) pv.hh[j] = __float2bfloat16(av[kh][h * 4 + j]);
            const size_t voff = (size_t)b * 262144
                + (size_t)(s * 4 + (ch >> 5) * 2 + (quad >> 1)) * 512
                + (size_t)(h * 32 + (ch & 31)) * 8
                + 4 * (quad & 1);
            *(unsigned long long*)(vb + voff) = pv.u;
        }
    }
}

// ---------------------------------------------------------------------------
// Kernel B v11: v7 (best, 45us) + ONE-PHASE SOFTWARE PIPELINE of S vs PV.
//   Per phase: ds_read K/V(cur) issued first; PV(prev) -- 8 register-only
//   MFMAs, no waitcnt -- executes UNDER the ds_read latency; then S(cur);
//   then exp2/pack(cur) whose packed P-frags (16 VGPR) + V-frags (32 VGPR)
//   carry to the next phase. Breaks the serial S->exp2->PV chain that caused
//   lockstep resonance (v6-v10: MfmaUtil+VALUBusy stuck <= 64%).
//   Explicit A/B register sets (no runtime indexing); phases 0,31 peeled.
//   Geometry = v7: grid (8,32) x 512 thr; 4 q-groups x 2 key-halves;
//   2 tiles/phase/wave; LDS 99840 B (1 block/CU, 2 waves/SIMD -- R10 proved
//   occupancy is not the limiter; ILP replaces TLP here).
// ---------------------------------------------------------------------------
__global__ __launch_bounds__(512, 2) void attn_fused(
    const __hip_bfloat16* __restrict__ qb,
    const __hip_bfloat16* __restrict__ kbf,
    const __hip_bfloat16* __restrict__ vbf,
    const float* __restrict__ wo, const float* __restrict__ bo,
    const float* __restrict__ x, float* __restrict__ y)
{
    __shared__ __align__(16) char  sm[2][8][4096];    // staging dbuf 64 KB
    __shared__ __align__(16) float REDx[4][64][33];   // epilogue partials 33792 B
    __shared__ float LRED2[4][32];                    // row-sums

    const int tid  = threadIdx.x;
    const int w    = tid >> 6;          // wave 0..7
    const int g    = w >> 1;            // q-group (32 rows)
    const int h    = w & 1;             // key half (2048 keys = 32 phases x 2 tiles)
    const int lane = tid & 63;
    const int q    = lane & 31;         // C/D column = q-row index
    const int hl   = lane >> 5;         // lane half
    const int b    = blockIdx.x;        // batch -> XCD affinity (lin%8 = b)
    const int row0 = blockIdx.y * 128 + g * 32;

    // Q B-frags (32x32x16): elem j at half hl -> dim kt*16 + hl*8 + j
    s16x8 qf[4];
    #pragma unroll
    for (int kt = 0; kt < 4; kt++)
        qf[kt] = *(const s16x8*)(qb + ((size_t)b * NPIX + row0 + q) * DIM
                                 + kt * 16 + hl * 8);

    f32x16 o0 = ZERO16, o1 = ZERO16;    // O^T[ch 0-31][q], O^T[ch 32-63][q]
    float lsacc = 0.f;                  // per-lane partial row-sum

    // staging: wave w stages one full 4 KB tile/phase, slot w.
    //   w = kv(1)|half_s(1)|sub(1):  kv = w>>2, half_s = (w>>1)&1, sub = w&1
    const char* stbase = ((w >> 2) ? (const char*)vbf : (const char*)kbf)
                       + (size_t)b * 524288
                       + (size_t)((w >> 1) & 1) * 262144    // 64 tiles per key-half
                       + (size_t)(w & 1) * 4096
                       + (size_t)lane * 16;
    char* std0 = &sm[0][w][lane * 16];
    char* std1 = &sm[1][w][lane * 16];

    // prologue: stage phase 0 into buf 0
    #pragma unroll
    for (int i = 0; i < 4; i++)
        *(f32x4*)(std0 + i * 1024) = *(const f32x4*)(stbase + i * 1024);
    __syncthreads();

    // pipeline state: V frags (8 x s16x8) + packed P frags (4 x s16x8) per set
    s16x8 vvA[8], vvB[8], pA[4], pB[4];

    // one phase: S/exp2 for phase p (buffer cur) -> (vvO,pO); PV for prev (vvP,pP)
    auto phase = [&](int p, int cur,
                     s16x8 (&vvP)[8], s16x8 (&pP)[4],
                     s16x8 (&vvO)[8], s16x8 (&pO)[4], bool do_pv) {
        // ds_reads issued first (stride-16 contiguous frags: conflict-free)
        const char* K0 = sm[cur][h * 2 + 0];
        const char* K1 = sm[cur][h * 2 + 1];
        const char* V0 = sm[cur][4 + h * 2 + 0];
        const char* V1 = sm[cur][4 + h * 2 + 1];
        s16x8 kf0[4], kf1[4];
        #pragma unroll
        for (int i = 0; i < 4; i++) {
            kf0[i]     = *(const s16x8*)(K0 + i * 1024 + lane * 16);
            kf1[i]     = *(const s16x8*)(K1 + i * 1024 + lane * 16);
            vvO[i]     = *(const s16x8*)(V0 + i * 1024 + lane * 16);
            vvO[4 + i] = *(const s16x8*)(V1 + i * 1024 + lane * 16);
        }
        // next-phase staging loads (global; land before the ds_write below)
        const size_t srcoff = (size_t)((p < 31) ? p + 1 : 31) * 8192;
        f32x4 r0 = *(const f32x4*)(stbase + srcoff);
        f32x4 r1 = *(const f32x4*)(stbase + srcoff + 1024);
        f32x4 r2 = *(const f32x4*)(stbase + srcoff + 2048);
        f32x4 r3 = *(const f32x4*)(stbase + srcoff + 3072);

        // PV(prev): register-only MFMAs -- execute under the ds_read latency
        if (do_pv) {
            __builtin_amdgcn_s_setprio(1);
            o0 = mfma32(vvP[0], pP[0], o0);
            o1 = mfma32(vvP[2], pP[0], o1);
            o0 = mfma32(vvP[1], pP[1], o0);
            o1 = mfma32(vvP[3], pP[1], o1);
            o0 = mfma32(vvP[4], pP[2], o0);
            o1 = mfma32(vvP[6], pP[2], o1);
            o0 = mfma32(vvP[5], pP[3], o0);
            o1 = mfma32(vvP[7], pP[3], o1);
            __builtin_amdgcn_s_setprio(0);
        }

        // S^T for the two current tiles (two independent 4-chains)
        __builtin_amdgcn_s_setprio(1);
        f32x16 s0 = ZERO16, s1 = ZERO16;
        s0 = mfma32(kf0[0], qf[0], s0);
        s1 = mfma32(kf1[0], qf[0], s1);
        s0 = mfma32(kf0[1], qf[1], s0);
        s1 = mfma32(kf1[1], qf[1], s1);
        s0 = mfma32(kf0[2], qf[2], s0);
        s1 = mfma32(kf1[2], qf[2], s1);
        s0 = mfma32(kf0[3], qf[3], s0);
        s1 = mfma32(kf1[3], qf[3], s1);
        __builtin_amdgcn_s_setprio(0);

        // exp2 + pack -> pO (carried to next phase); VALU row-sum
        union { s16x8 v; __hip_bfloat16 h8[8]; } u0, u1, u2, u3;
        #pragma unroll
        for (int j = 0; j < 8; j++) {
            float e0 = EXP2(s0[j]);
            float e1 = EXP2(s0[8 + j]);
            lsacc += e0 + e1;
            u0.h8[j] = __float2bfloat16(e0);
            u1.h8[j] = __float2bfloat16(e1);
        }
        #pragma unroll
        for (int j = 0; j < 8; j++) {
            float e0 = EXP2(s1[j]);
            float e1 = EXP2(s1[8 + j]);
            lsacc += e0 + e1;
            u2.h8[j] = __float2bfloat16(e0);
            u3.h8[j] = __float2bfloat16(e1);
        }
        pO[0] = u0.v; pO[1] = u1.v; pO[2] = u2.v; pO[3] = u3.v;

        // write staged tile into the other buffer, then phase barrier
        char* dst = cur ? std0 : std1;
        *(f32x4*)(dst)        = r0;
        *(f32x4*)(dst + 1024) = r1;
        *(f32x4*)(dst + 2048) = r2;
        *(f32x4*)(dst + 3072) = r3;
        __syncthreads();
    };

    // phase 0: no PV yet -> produces A
    phase(0, 0, vvB, pB, vvA, pA, false);
    // phases 1..30: ping-pong A/B
    for (int it = 0; it < 15; ++it) {
        phase(2 * it + 1, 1, vvA, pA, vvB, pB, true);
        phase(2 * it + 2, 0, vvB, pB, vvA, pA, true);
    }
    // phase 31: PV(A) -> produces B
    phase(31, 1, vvA, pA, vvB, pB, true);
    // epilogue PV(B)
    __builtin_amdgcn_s_setprio(1);
    o0 = mfma32(vvB[0], pB[0], o0);
    o1 = mfma32(vvB[2], pB[0], o1);
    o0 = mfma32(vvB[1], pB[1], o0);
    o1 = mfma32(vvB[3], pB[1], o1);
    o0 = mfma32(vvB[4], pB[2], o0);
    o1 = mfma32(vvB[6], pB[2], o1);
    o0 = mfma32(vvB[5], pB[3], o0);
    o1 = mfma32(vvB[7], pB[3], o1);
    __builtin_amdgcn_s_setprio(0);

    // cross-half row-sum combine (both lane-halves hold same q, disjoint keys)
    lsacc += __shfl_xor(lsacc, 32, 64);

    // ---- combine the two key-halves per q-group ----
    if (h == 1) {
        #pragma unroll
        for (int i = 0; i < 16; i++) {
            const int rr = (i & 3) + 8 * (i >> 2) + 4 * hl;
            REDx[g][rr][q]      = o0[i];
            REDx[g][32 + rr][q] = o1[i];
        }
        if (hl == 0) LRED2[g][q] = lsacc;
    }
    __syncthreads();

    if (h == 0) {
        const float lsum = lsacc + LRED2[g][q];
        #pragma unroll
        for (int i = 0; i < 16; i++) {
            const int rr = (i & 3) + 8 * (i >> 2) + 4 * hl;
            o0[i] += REDx[g][rr][q];
            o1[i] += REDx[g][32 + rr][q];
        }
        const float inv = 1.0f / lsum;

        // normalized O^T -> B-frags per 16-ch group (direct from registers)
        s16x8 pbo[4];
        #pragma unroll
        for (int gg = 0; gg < 4; gg++) {
            union { s16x8 v; __hip_bfloat16 h8[8]; } pk;
            #pragma unroll
            for (int j = 0; j < 8; j++) {
                const float vv2 = (gg < 2) ? o0[(gg & 1) * 8 + j] : o1[(gg & 1) * 8 + j];
                pk.h8[j] = __float2bfloat16(vv2 * inv);
            }
            pbo[gg] = pk.v;
        }

        // wo A-frags with the key/ch relabeling mu(gg,hl,j)
        s16x8 aw[4];
        #pragma unroll
        for (int gg = 0; gg < 4; gg++) {
            f32x4 w0 = *(const f32x4*)(wo + (size_t)q * DIM + gg * 16 + hl * 4);
            f32x4 w1 = *(const f32x4*)(wo + (size_t)q * DIM + gg * 16 + 8 + hl * 4);
            union { s16x8 v; __hip_bfloat16 h8[8]; } wf;
            #pragma unroll
            for (int j = 0; j < 4; j++) {
                wf.h8[j]     = __float2bfloat16(w0[j]);
                wf.h8[4 + j] = __float2bfloat16(w1[j]);
            }
            aw[gg] = wf.v;
        }

        // Y^T[out][q] = wo x ONorm^T  (single 32x32 tile, K=64 over 4 mfmas)
        f32x16 d = ZERO16;
        #pragma unroll
        for (int gg = 0; gg < 4; gg++)
            d = mfma32(aw[gg], pbo[gg], d);

        // bias + residual + store y (B, 32, 4096) fp32
        #pragma unroll
        for (int i = 0; i < 16; i++) {
            const int out = (i & 3) + 8 * (i >> 2) + 4 * hl;
            const int row = row0 + q;
            const size_t xi = ((size_t)b * CIN + out) * NPIX + row;
            y[xi] = d[i] + bo[out] + x[xi];
        }
    }
}

// ---------------------------------------------------------------------------
extern "C" void kernel_launch(void* const* d_in, const int* in_sizes, int n_in,
                              void* d_out, int out_size, void* d_ws, size_t ws_size,
                              hipStream_t stream)
{
    const float* x  = (const float*)d_in[0];
    const float* wq = (const float*)d_in[1];
    const float* bq = (const float*)d_in[2];
    const float* wk = (const float*)d_in[3];
    const float* bk = (const float*)d_in[4];
    const float* wv = (const float*)d_in[5];
    const float* bv = (const float*)d_in[6];
    const float* wo = (const float*)d_in[7];
    const float* bo = (const float*)d_in[8];
    float* y = (float*)d_out;

    // workspace: qb 4MB (row-major, log2e-scaled) | kb 4MB | vb 4MB (frag orders)
    char* ws = (char*)d_ws;
    __hip_bfloat16* qb = (__hip_bfloat16*)(ws);
    __hip_bfloat16* kb = (__hip_bfloat16*)(ws + (4u << 20));
    __hip_bfloat16* vb = (__hip_bfloat16*)(ws + (8u << 20));

    qkv_proj<<<dim3(64, 8), dim3(256), 0, stream>>>(x, wq, bq, wk, bk, wv, bv, qb, kb, vb);
    attn_fused<<<dim3(8, 32), dim3(512), 0, stream>>>(qb, kb, vb, wo, bo, x, y);
}